// Round 3
// baseline (2046.965 us; speedup 1.0000x reference)
//
#include <hip/hip_runtime.h>

typedef short bf16x8 __attribute__((ext_vector_type(8)));
typedef float f32x4 __attribute__((ext_vector_type(4)));

#define TOKS 8192
#define DDIM 1024
#define HDIM 2048
#define NEXP 8
#define ROWS_TOTAL (2 * TOKS)  // K=2 assignments total

__device__ __forceinline__ unsigned short f2b(float f) {
  unsigned int x;
  __builtin_memcpy(&x, &f, 4);
  return (unsigned short)((x + 0x7fffu + ((x >> 16) & 1u)) >> 16);  // RNE
}

// ---------------- Router: one wave per token (fp32 in) ----------------
__global__ __launch_bounds__(256) void router_kernel(
    const float* __restrict__ x, const float* __restrict__ Wg,
    const float* __restrict__ bg, int* __restrict__ counts,
    int* __restrict__ tok_ids, float* __restrict__ gates) {
  int lane = threadIdx.x & 63;
  int t = blockIdx.x * 4 + (threadIdx.x >> 6);
  const float* xr = x + (size_t)t * DDIM;
  float acc[NEXP];
#pragma unroll
  for (int e = 0; e < NEXP; ++e) acc[e] = 0.f;
#pragma unroll
  for (int jj = 0; jj < DDIM / 64; ++jj) {
    int d = jj * 64 + lane;
    float xv = xr[d];
    float4 w0 = *(const float4*)(Wg + d * NEXP);
    float4 w1v = *(const float4*)(Wg + d * NEXP + 4);
    acc[0] += xv * w0.x; acc[1] += xv * w0.y; acc[2] += xv * w0.z; acc[3] += xv * w0.w;
    acc[4] += xv * w1v.x; acc[5] += xv * w1v.y; acc[6] += xv * w1v.z; acc[7] += xv * w1v.w;
  }
#pragma unroll
  for (int off = 32; off > 0; off >>= 1) {
#pragma unroll
    for (int e = 0; e < NEXP; ++e) acc[e] += __shfl_down(acc[e], off, 64);
  }
  if (lane == 0) {
    float v[NEXP];
#pragma unroll
    for (int e = 0; e < NEXP; ++e) v[e] = acc[e] + bg[e];
    int e0 = 0;
    float v0 = v[0];
#pragma unroll
    for (int e = 1; e < NEXP; ++e)
      if (v[e] > v0) { v0 = v[e]; e0 = e; }  // strict > keeps lowest index (jax tie rule)
    int e1 = -1;
    float v1 = -3.4e38f;
#pragma unroll
    for (int e = 0; e < NEXP; ++e)
      if (e != e0 && v[e] > v1) { v1 = v[e]; e1 = e; }
    if (e1 < 0) e1 = (e0 + 1) & 7;       // NaN hard-guard: never emit invalid index
    float ex = __expf(v1 - v0);          // softmax over top-2
    float g0 = 1.f / (1.f + ex);
    float g1 = 1.f - g0;
    int s0 = atomicAdd(&counts[e0], 1);
    if (s0 < TOKS) { tok_ids[e0 * TOKS + s0] = t; gates[e0 * TOKS + s0] = g0; }
    int s1 = atomicAdd(&counts[e1], 1);
    if (s1 < TOKS) { tok_ids[e1 * TOKS + s1] = t; gates[e1 * TOKS + s1] = g1; }
  }
}

// ---------------- Tiny prefix sum over expert counts ----------------
__global__ void offsets_kernel(const int* __restrict__ counts, int* __restrict__ offsets) {
  if (threadIdx.x == 0) {
    int o = 0;
    for (int e = 0; e < NEXP; ++e) { offsets[e] = o; o += counts[e]; }
  }
}

// ---------------- Stage A: h[:, nbase:nbase+hw] = silu(x@w1)*(x@w3) ----------------
__global__ __launch_bounds__(256) void ffn1_kernel(
    const float* __restrict__ x, const float* __restrict__ w1,
    const float* __restrict__ w3, const int* __restrict__ tok_ids,
    const int* __restrict__ counts, const int* __restrict__ offsets,
    unsigned short* __restrict__ h, int nbase, int hw) {
  int e = blockIdx.z;
  int count = counts[e];
  int mbase = blockIdx.x * 128;
  if (mbase >= count) return;
  int off = offsets[e];
  int n0 = nbase + blockIdx.y * 128;  // global column into H
  const float* w1e = w1 + (size_t)e * DDIM * HDIM;
  const float* w3e = w3 + (size_t)e * DDIM * HDIM;
  const int* tok_e = tok_ids + e * TOKS;

  __shared__ unsigned short sA[128][40];   // [m][k] bf16, +8 pad: 2-way conflicts only
  __shared__ unsigned short sB1[128][40];  // [n][k] (transposed + cvt at stage time)
  __shared__ unsigned short sB3[128][40];
  __shared__ int stok[128];

  int tid = threadIdx.x;
  if (tid < 128) {
    int slot = mbase + tid;
    if (slot >= count) slot = count - 1;  // clamp: garbage rows masked at store
    if (slot < 0) slot = 0;
    stok[tid] = tok_e[slot];
  }

  int lane = tid & 63;
  int wv = tid >> 6;
  int wm = wv >> 1, wn = wv & 1;
  int rsel = lane & 15, q = lane >> 4;

  f32x4 acc1[4][4], acc3[4][4];
#pragma unroll
  for (int i = 0; i < 4; ++i)
#pragma unroll
    for (int j = 0; j < 4; ++j) {
      f32x4 z = {0.f, 0.f, 0.f, 0.f};
      acc1[i][j] = z;
      acc3[i][j] = z;
    }

  for (int k0 = 0; k0 < DDIM; k0 += 32) {
    __syncthreads();
#pragma unroll
    for (int cc = 0; cc < 2; ++cc) {
      int c = tid + cc * 256;
      int r = c >> 2, kg = c & 3;
      // A tile: token-gathered rows, 8 fp32 -> 8 bf16 -> one b128 LDS write
      const float* ax = x + (size_t)stok[r] * DDIM + k0 + kg * 8;
      float4 a0 = *(const float4*)ax;
      float4 a1 = *(const float4*)(ax + 4);
      union { int4 v; unsigned short u[8]; } ua;
      ua.u[0] = f2b(a0.x); ua.u[1] = f2b(a0.y); ua.u[2] = f2b(a0.z); ua.u[3] = f2b(a0.w);
      ua.u[4] = f2b(a1.x); ua.u[5] = f2b(a1.y); ua.u[6] = f2b(a1.z); ua.u[7] = f2b(a1.w);
      *(int4*)&sA[r][kg * 8] = ua.v;
      // B tiles: strided 4B loads (lanes contiguous across r) -> cvt -> packed write
      const float* p1 = w1e + (size_t)(k0 + kg * 8) * HDIM + n0 + r;
      const float* p3 = w3e + (size_t)(k0 + kg * 8) * HDIM + n0 + r;
      union { int4 v; unsigned short u[8]; } t1, t3;
#pragma unroll
      for (int j = 0; j < 8; ++j) {
        t1.u[j] = f2b(p1[(size_t)j * HDIM]);
        t3.u[j] = f2b(p3[(size_t)j * HDIM]);
      }
      *(int4*)&sB1[r][kg * 8] = t1.v;
      *(int4*)&sB3[r][kg * 8] = t3.v;
    }
    __syncthreads();

    bf16x8 aF[4], bF1[4], bF3[4];
#pragma unroll
    for (int mi = 0; mi < 4; ++mi)
      aF[mi] = *(const bf16x8*)&sA[wm * 64 + mi * 16 + rsel][q * 8];
#pragma unroll
    for (int ni = 0; ni < 4; ++ni) {
      bF1[ni] = *(const bf16x8*)&sB1[wn * 64 + ni * 16 + rsel][q * 8];
      bF3[ni] = *(const bf16x8*)&sB3[wn * 64 + ni * 16 + rsel][q * 8];
    }
#pragma unroll
    for (int mi = 0; mi < 4; ++mi)
#pragma unroll
      for (int ni = 0; ni < 4; ++ni) {
        acc1[mi][ni] = __builtin_amdgcn_mfma_f32_16x16x32_bf16(aF[mi], bF1[ni], acc1[mi][ni], 0, 0, 0);
        acc3[mi][ni] = __builtin_amdgcn_mfma_f32_16x16x32_bf16(aF[mi], bF3[ni], acc3[mi][ni], 0, 0, 0);
      }
  }

  int cm = count - mbase;
#pragma unroll
  for (int mi = 0; mi < 4; ++mi) {
#pragma unroll
    for (int rr = 0; rr < 4; ++rr) {
      int m = wm * 64 + mi * 16 + q * 4 + rr;  // C/D: row = quad*4+reg
      if (m < cm) {
#pragma unroll
        for (int ni = 0; ni < 4; ++ni) {
          int nl = blockIdx.y * 128 + wn * 64 + ni * 16 + rsel;  // local col in chunk
          float u = acc1[mi][ni][rr];
          float vv = acc3[mi][ni][rr];
          float hv = (u / (1.f + __expf(-u))) * vv;  // silu(u)*v
          h[(size_t)(off + mbase + m) * hw + nl] = f2b(hv);
        }
      }
    }
  }
}

// ---------------- Stage B: out[tok] += gate * (h_chunk @ w2[kbase:,:]) ----------------
__global__ __launch_bounds__(256) void ffn2_kernel(
    const unsigned short* __restrict__ h, const float* __restrict__ w2,
    const int* __restrict__ tok_ids, const float* __restrict__ gates,
    const int* __restrict__ counts, const int* __restrict__ offsets,
    float* __restrict__ out, int kbase, int hw) {
  int e = blockIdx.z;
  int count = counts[e];
  int mbase = blockIdx.x * 128;
  if (mbase >= count) return;
  int off = offsets[e];
  int n0 = blockIdx.y * 128;
  const float* w2e = w2 + (size_t)e * HDIM * DDIM;

  __shared__ unsigned short sA[128][40];
  __shared__ unsigned short sB[128][40];
  __shared__ int stok[128];
  __shared__ float sg[128];

  int tid = threadIdx.x;
  if (tid < 128) {
    int slot = mbase + tid;
    if (slot >= count) slot = count - 1;
    if (slot < 0) slot = 0;
    stok[tid] = tok_ids[e * TOKS + slot];
    sg[tid] = gates[e * TOKS + slot];
  }

  int lane = tid & 63;
  int wv = tid >> 6;
  int wm = wv >> 1, wn = wv & 1;
  int rsel = lane & 15, q = lane >> 4;

  f32x4 acc[4][4];
#pragma unroll
  for (int i = 0; i < 4; ++i)
#pragma unroll
    for (int j = 0; j < 4; ++j) {
      f32x4 z = {0.f, 0.f, 0.f, 0.f};
      acc[i][j] = z;
    }

  for (int k0 = 0; k0 < hw; k0 += 32) {
    __syncthreads();
#pragma unroll
    for (int cc = 0; cc < 2; ++cc) {
      int c = tid + cc * 256;
      int r = c >> 2, kg = c & 3;
      int slot = mbase + r;
      if (slot >= count) slot = count - 1;
      // h already bf16: straight 16B copy
      *(int4*)&sA[r][kg * 8] = *(const int4*)(h + (size_t)(off + slot) * hw + k0 + kg * 8);
      const float* p2 = w2e + (size_t)(kbase + k0 + kg * 8) * DDIM + n0 + r;
      union { int4 v; unsigned short u[8]; } t2;
#pragma unroll
      for (int j = 0; j < 8; ++j) t2.u[j] = f2b(p2[(size_t)j * DDIM]);
      *(int4*)&sB[r][kg * 8] = t2.v;
    }
    __syncthreads();

    bf16x8 aF[4], bF[4];
#pragma unroll
    for (int mi = 0; mi < 4; ++mi)
      aF[mi] = *(const bf16x8*)&sA[wm * 64 + mi * 16 + rsel][q * 8];
#pragma unroll
    for (int ni = 0; ni < 4; ++ni)
      bF[ni] = *(const bf16x8*)&sB[wn * 64 + ni * 16 + rsel][q * 8];
#pragma unroll
    for (int mi = 0; mi < 4; ++mi)
#pragma unroll
      for (int ni = 0; ni < 4; ++ni)
        acc[mi][ni] = __builtin_amdgcn_mfma_f32_16x16x32_bf16(aF[mi], bF[ni], acc[mi][ni], 0, 0, 0);
  }

  int cm = count - mbase;
#pragma unroll
  for (int mi = 0; mi < 4; ++mi) {
#pragma unroll
    for (int rr = 0; rr < 4; ++rr) {
      int m = wm * 64 + mi * 16 + q * 4 + rr;
      if (m < cm) {
        int t = stok[m];
        float g = sg[m];
#pragma unroll
        for (int ni = 0; ni < 4; ++ni) {
          int col = n0 + wn * 64 + ni * 16 + rsel;
          // out is fp32: accumulate directly (each element gets exactly 2 adds)
          atomicAdd(&out[(size_t)t * DDIM + col], g * acc[mi][ni][rr]);
        }
      }
    }
  }
}

extern "C" void kernel_launch(void* const* d_in, const int* in_sizes, int n_in,
                              void* d_out, int out_size, void* d_ws, size_t ws_size,
                              hipStream_t stream) {
  (void)in_sizes; (void)n_in; (void)out_size;
  const float* x  = (const float*)d_in[0];
  const float* Wg = (const float*)d_in[1];
  const float* bg = (const float*)d_in[2];
  const float* w1 = (const float*)d_in[3];
  const float* w3 = (const float*)d_in[4];
  const float* w2 = (const float*)d_in[5];
  float* out = (float*)d_out;

  // ws layout: routing arrays (0.5 MB) + bf16 h buffer (chunk-sized to fit ws)
  char* ws = (char*)d_ws;
  int*   tok_ids = (int*)ws;               // NEXP*TOKS*4 = 262144
  float* gates   = (float*)(ws + 262144);  // 262144
  int*   counts  = (int*)(ws + 524288);    // 32 (+pad)
  int*   offsets = (int*)(ws + 524352);    // 32
  const size_t used0 = 1 << 20;
  size_t avail = (ws_size > used0) ? ws_size - used0 : 0;

  int hw = 128;  // minimum chunk (needs 4 MB h)
  const int cand[5] = {2048, 1024, 512, 256, 128};
  for (int i = 0; i < 5; ++i)
    if ((size_t)ROWS_TOTAL * cand[i] * 2 <= avail) { hw = cand[i]; break; }
  unsigned short* hbuf = (unsigned short*)(ws + used0);

  hipMemsetAsync(counts, 0, 128, stream);
  hipMemsetAsync(out, 0, (size_t)TOKS * DDIM * sizeof(float), stream);

  router_kernel<<<TOKS / 4, 256, 0, stream>>>(x, Wg, bg, counts, tok_ids, gates);
  offsets_kernel<<<1, 64, 0, stream>>>(counts, offsets);

  for (int nbase = 0; nbase < HDIM; nbase += hw) {
    ffn1_kernel<<<dim3(64, hw / 128, NEXP), 256, 0, stream>>>(
        x, w1, w3, tok_ids, counts, offsets, hbuf, nbase, hw);
    ffn2_kernel<<<dim3(64, DDIM / 128, NEXP), 256, 0, stream>>>(
        hbuf, w2, tok_ids, gates, counts, offsets, out, nbase, hw);
  }
}

// Round 4
// 1233.819 us; speedup vs baseline: 1.6590x; 1.6590x over previous
//
#include <hip/hip_runtime.h>

typedef short bf16x8 __attribute__((ext_vector_type(8)));
typedef float f32x4 __attribute__((ext_vector_type(4)));
typedef unsigned short u16;
typedef unsigned int u32;

#define TOKS 8192
#define DDIM 1024
#define HDIM 2048
#define NEXP 8
#define ROWS_TOTAL (2 * TOKS)

__device__ __forceinline__ u16 f2b(float f) {
  u32 x;
  __builtin_memcpy(&x, &f, 4);
  return (u16)((x + 0x7fffu + ((x >> 16) & 1u)) >> 16);  // RNE
}

// async global->LDS, 16B per lane. LDS side: wave-uniform base + lane*16.
typedef const __attribute__((address_space(1))) u32* gp_t;
typedef __attribute__((address_space(3))) u32* lp_t;
__device__ __forceinline__ void glds16(const void* g, void* l) {
  __builtin_amdgcn_global_load_lds((gp_t)g, (lp_t)l, 16, 0, 0);
}

// ---------------- x fp32 -> bf16 (layout kept) ----------------
__global__ __launch_bounds__(256) void cvt_x_kernel(const float* __restrict__ in,
                                                    u16* __restrict__ out) {
  size_t i = ((size_t)blockIdx.x * 256 + threadIdx.x) * 8;
  float4 a = *(const float4*)(in + i);
  float4 b = *(const float4*)(in + i + 4);
  union { int4 v; u16 u[8]; } o;
  o.u[0] = f2b(a.x); o.u[1] = f2b(a.y); o.u[2] = f2b(a.z); o.u[3] = f2b(a.w);
  o.u[4] = f2b(b.x); o.u[5] = f2b(b.y); o.u[6] = f2b(b.z); o.u[7] = f2b(b.w);
  *(int4*)(out + i) = o.v;
}

// ---------------- weight [K][N] fp32 -> [N][K] bf16 (64x64 LDS transpose) ----------------
__global__ __launch_bounds__(256) void cvt_wT_kernel(const float* __restrict__ in,
                                                     u16* __restrict__ out, int K, int N) {
  size_t eo = (size_t)blockIdx.z * K * N;
  in += eo; out += eo;
  int n0 = blockIdx.x * 64, k0 = blockIdx.y * 64;
  __shared__ u16 s[64][72];
  int tid = threadIdx.x;
  int kr = tid >> 4, nc = (tid & 15) * 4;
#pragma unroll
  for (int i = 0; i < 4; ++i) {
    int k = k0 + i * 16 + kr;
    float4 v = *(const float4*)(in + (size_t)k * N + n0 + nc);
    ushort4 u;
    u.x = f2b(v.x); u.y = f2b(v.y); u.z = f2b(v.z); u.w = f2b(v.w);
    *(ushort4*)&s[i * 16 + kr][nc] = u;
  }
  __syncthreads();
  int nl = tid >> 2, kc = tid & 3;
  union { int4 v[2]; u16 u[16]; } o;
#pragma unroll
  for (int j = 0; j < 16; ++j) o.u[j] = s[kc * 16 + j][nl];
  u16* op = out + (size_t)(n0 + nl) * K + k0 + kc * 16;
  *(int4*)op = o.v[0];
  *(int4*)(op + 8) = o.v[1];
}

// ---------------- Router: one wave per token (fp32 in) ----------------
__global__ __launch_bounds__(256) void router_kernel(
    const float* __restrict__ x, const float* __restrict__ Wg,
    const float* __restrict__ bg, int* __restrict__ counts,
    int* __restrict__ tok_ids, float* __restrict__ gates) {
  int lane = threadIdx.x & 63;
  int t = blockIdx.x * 4 + (threadIdx.x >> 6);
  const float* xr = x + (size_t)t * DDIM;
  float acc[NEXP];
#pragma unroll
  for (int e = 0; e < NEXP; ++e) acc[e] = 0.f;
#pragma unroll
  for (int jj = 0; jj < DDIM / 64; ++jj) {
    int d = jj * 64 + lane;
    float xv = xr[d];
    float4 w0 = *(const float4*)(Wg + d * NEXP);
    float4 w1v = *(const float4*)(Wg + d * NEXP + 4);
    acc[0] += xv * w0.x; acc[1] += xv * w0.y; acc[2] += xv * w0.z; acc[3] += xv * w0.w;
    acc[4] += xv * w1v.x; acc[5] += xv * w1v.y; acc[6] += xv * w1v.z; acc[7] += xv * w1v.w;
  }
#pragma unroll
  for (int off = 32; off > 0; off >>= 1) {
#pragma unroll
    for (int e = 0; e < NEXP; ++e) acc[e] += __shfl_down(acc[e], off, 64);
  }
  if (lane == 0) {
    float v[NEXP];
#pragma unroll
    for (int e = 0; e < NEXP; ++e) v[e] = acc[e] + bg[e];
    int e0 = 0;
    float v0 = v[0];
#pragma unroll
    for (int e = 1; e < NEXP; ++e)
      if (v[e] > v0) { v0 = v[e]; e0 = e; }  // strict >: lowest index wins ties (jax)
    int e1 = -1;
    float v1 = -3.4e38f;
#pragma unroll
    for (int e = 0; e < NEXP; ++e)
      if (e != e0 && v[e] > v1) { v1 = v[e]; e1 = e; }
    if (e1 < 0) e1 = (e0 + 1) & 7;  // NaN hard-guard
    float ex = __expf(v1 - v0);
    float g0 = 1.f / (1.f + ex);
    float g1 = 1.f - g0;
    int s0 = atomicAdd(&counts[e0], 1);
    if (s0 < TOKS) { tok_ids[e0 * TOKS + s0] = t; gates[e0 * TOKS + s0] = g0; }
    int s1 = atomicAdd(&counts[e1], 1);
    if (s1 < TOKS) { tok_ids[e1 * TOKS + s1] = t; gates[e1 * TOKS + s1] = g1; }
  }
}

__global__ void offsets_kernel(const int* __restrict__ counts, int* __restrict__ offsets) {
  if (threadIdx.x == 0) {
    int o = 0;
    for (int e = 0; e < NEXP; ++e) { offsets[e] = o; o += counts[e]; }
  }
}

// ---------------- Stage A: h = silu(xb@w1t^T)*(xb@w3t^T) ----------------
// w1t/w3t: [N=HDIM][K=DDIM] bf16. LDS rows packed 64B + XOR swizzle on global chunk.
__global__ __launch_bounds__(256) void ffn1_kernel(
    const u16* __restrict__ xb, const u16* __restrict__ w1t,
    const u16* __restrict__ w3t, const int* __restrict__ tok_ids,
    const int* __restrict__ counts, const int* __restrict__ offsets,
    u16* __restrict__ h, int nbase, int hw, int e_arg) {
  int e = (e_arg >= 0) ? e_arg : (int)blockIdx.z;
  int count = counts[e];
  int mbase = blockIdx.x * 128;
  if (mbase >= count) return;
  int row_off = (e_arg >= 0) ? 0 : offsets[e];
  int n0g = nbase + blockIdx.y * 128;
  size_t we = (e_arg >= 0) ? 0 : (size_t)e;
  const u16* w1e = w1t + we * (size_t)(HDIM * DDIM);
  const u16* w3e = w3t + we * (size_t)(HDIM * DDIM);

  __shared__ u16 sA[128 * 32];
  __shared__ u16 sB1[128 * 32];
  __shared__ u16 sB3[128 * 32];
  __shared__ int stok[128];

  int tid = threadIdx.x, lane = tid & 63, wv = tid >> 6;
  if (tid < 128) {
    int s = mbase + tid;
    if (s >= count) s = count - 1;
    stok[tid] = tok_ids[e * TOKS + s];
  }
  __syncthreads();

  // per-wave staging: 24 segments of 1KB (16 rows x 64B); 6 per wave
  int rloc = lane >> 2, ch = lane & 3;
  const u16* gsrc[6];
  u16* ldst[6];
#pragma unroll
  for (int i = 0; i < 6; ++i) {
    int s = wv * 6 + i;
    if (s < 8) {
      int r = s * 16 + rloc;
      int sw = ch ^ ((r >> 1) & 3);
      gsrc[i] = xb + (size_t)stok[r] * DDIM + sw * 8;
      ldst[i] = sA + s * 512;
    } else if (s < 16) {
      int r = (s - 8) * 16 + rloc;
      int sw = ch ^ ((r >> 1) & 3);
      gsrc[i] = w1e + (size_t)(n0g + r) * DDIM + sw * 8;
      ldst[i] = sB1 + (s - 8) * 512;
    } else {
      int r = (s - 16) * 16 + rloc;
      int sw = ch ^ ((r >> 1) & 3);
      gsrc[i] = w3e + (size_t)(n0g + r) * DDIM + sw * 8;
      ldst[i] = sB3 + (s - 16) * 512;
    }
  }

  int wm = wv >> 1, wn = wv & 1;
  int rsel = lane & 15, q = lane >> 4;

  f32x4 acc1[4][4], acc3[4][4];
#pragma unroll
  for (int i = 0; i < 4; ++i)
#pragma unroll
    for (int j = 0; j < 4; ++j) {
      f32x4 z = {0.f, 0.f, 0.f, 0.f};
      acc1[i][j] = z; acc3[i][j] = z;
    }

  for (int k0 = 0; k0 < DDIM; k0 += 32) {
    __syncthreads();  // LDS reuse guard
#pragma unroll
    for (int i = 0; i < 6; ++i) glds16(gsrc[i] + k0, ldst[i]);
    __syncthreads();  // drains vmcnt for the async loads

    bf16x8 aF[4], b1F[4], b3F[4];
#pragma unroll
    for (int mi = 0; mi < 4; ++mi) {
      int r = wm * 64 + mi * 16 + rsel;
      int p = q ^ ((r >> 1) & 3);
      aF[mi] = *(const bf16x8*)&sA[r * 32 + p * 8];
    }
#pragma unroll
    for (int ni = 0; ni < 4; ++ni) {
      int r = wn * 64 + ni * 16 + rsel;
      int p = q ^ ((r >> 1) & 3);
      b1F[ni] = *(const bf16x8*)&sB1[r * 32 + p * 8];
      b3F[ni] = *(const bf16x8*)&sB3[r * 32 + p * 8];
    }
#pragma unroll
    for (int mi = 0; mi < 4; ++mi)
#pragma unroll
      for (int ni = 0; ni < 4; ++ni) {
        acc1[mi][ni] = __builtin_amdgcn_mfma_f32_16x16x32_bf16(aF[mi], b1F[ni], acc1[mi][ni], 0, 0, 0);
        acc3[mi][ni] = __builtin_amdgcn_mfma_f32_16x16x32_bf16(aF[mi], b3F[ni], acc3[mi][ni], 0, 0, 0);
      }
  }

  int cm = count - mbase;
#pragma unroll
  for (int mi = 0; mi < 4; ++mi) {
#pragma unroll
    for (int rr = 0; rr < 4; ++rr) {
      int m = wm * 64 + mi * 16 + q * 4 + rr;  // C/D: row = quad*4+reg
      if (m < cm) {
#pragma unroll
        for (int ni = 0; ni < 4; ++ni) {
          int nl = blockIdx.y * 128 + wn * 64 + ni * 16 + rsel;  // local col in chunk
          float u = acc1[mi][ni][rr];
          float vv = acc3[mi][ni][rr];
          float hv = (u / (1.f + __expf(-u))) * vv;  // silu(u)*v
          h[(size_t)(row_off + mbase + m) * hw + nl] = f2b(hv);
        }
      }
    }
  }
}

// ---------------- Stage B: out[tok] += gate * (h @ w2t^T) ----------------
// w2t: [N=DDIM][K=HDIM] bf16.
__global__ __launch_bounds__(256) void ffn2_kernel(
    const u16* __restrict__ h, const u16* __restrict__ w2t,
    const int* __restrict__ tok_ids, const float* __restrict__ gates,
    const int* __restrict__ counts, const int* __restrict__ offsets,
    float* __restrict__ out, int kbase, int hw, int e_arg) {
  int e = (e_arg >= 0) ? e_arg : (int)blockIdx.z;
  int count = counts[e];
  int mbase = blockIdx.x * 128;
  if (mbase >= count) return;
  int row_off = (e_arg >= 0) ? 0 : offsets[e];
  int n0 = blockIdx.y * 128;
  size_t we = (e_arg >= 0) ? 0 : (size_t)e;
  const u16* w2e = w2t + we * (size_t)(HDIM * DDIM);

  __shared__ u16 sA[128 * 32];
  __shared__ u16 sB[128 * 32];
  __shared__ int stok[128];
  __shared__ float sg[128];

  int tid = threadIdx.x, lane = tid & 63, wv = tid >> 6;
  if (tid < 128) {
    int s = mbase + tid;
    if (s >= count) s = count - 1;
    stok[tid] = tok_ids[e * TOKS + s];
    sg[tid] = gates[e * TOKS + s];
  }
  __syncthreads();

  int rloc = lane >> 2, ch = lane & 3;
  const u16* gsrc[4];
  u16* ldst[4];
#pragma unroll
  for (int i = 0; i < 4; ++i) {
    int s = wv * 4 + i;
    if (s < 8) {
      int r = s * 16 + rloc;
      int slot = mbase + r;
      if (slot >= count) slot = count - 1;
      int sw = ch ^ ((r >> 1) & 3);
      gsrc[i] = h + (size_t)(row_off + slot) * hw + sw * 8;
      ldst[i] = sA + s * 512;
    } else {
      int r = (s - 8) * 16 + rloc;
      int sw = ch ^ ((r >> 1) & 3);
      gsrc[i] = w2e + (size_t)(n0 + r) * HDIM + kbase + sw * 8;
      ldst[i] = sB + (s - 8) * 512;
    }
  }

  int wm = wv >> 1, wn = wv & 1;
  int rsel = lane & 15, q = lane >> 4;

  f32x4 acc[4][4];
#pragma unroll
  for (int i = 0; i < 4; ++i)
#pragma unroll
    for (int j = 0; j < 4; ++j) {
      f32x4 z = {0.f, 0.f, 0.f, 0.f};
      acc[i][j] = z;
    }

  for (int k0 = 0; k0 < hw; k0 += 32) {
    __syncthreads();
#pragma unroll
    for (int i = 0; i < 4; ++i) glds16(gsrc[i] + k0, ldst[i]);
    __syncthreads();

    bf16x8 aF[4], bF[4];
#pragma unroll
    for (int mi = 0; mi < 4; ++mi) {
      int r = wm * 64 + mi * 16 + rsel;
      int p = q ^ ((r >> 1) & 3);
      aF[mi] = *(const bf16x8*)&sA[r * 32 + p * 8];
    }
#pragma unroll
    for (int ni = 0; ni < 4; ++ni) {
      int r = wn * 64 + ni * 16 + rsel;
      int p = q ^ ((r >> 1) & 3);
      bF[ni] = *(const bf16x8*)&sB[r * 32 + p * 8];
    }
#pragma unroll
    for (int mi = 0; mi < 4; ++mi)
#pragma unroll
      for (int ni = 0; ni < 4; ++ni)
        acc[mi][ni] = __builtin_amdgcn_mfma_f32_16x16x32_bf16(aF[mi], bF[ni], acc[mi][ni], 0, 0, 0);
  }

  int cm = count - mbase;
#pragma unroll
  for (int mi = 0; mi < 4; ++mi) {
#pragma unroll
    for (int rr = 0; rr < 4; ++rr) {
      int m = wm * 64 + mi * 16 + q * 4 + rr;
      if (m < cm) {
        int t = stok[m];
        float g = sg[m];
#pragma unroll
        for (int ni = 0; ni < 4; ++ni) {
          int col = n0 + wn * 64 + ni * 16 + rsel;
          atomicAdd(&out[(size_t)t * DDIM + col], g * acc[mi][ni][rr]);
        }
      }
    }
  }
}

extern "C" void kernel_launch(void* const* d_in, const int* in_sizes, int n_in,
                              void* d_out, int out_size, void* d_ws, size_t ws_size,
                              hipStream_t stream) {
  (void)in_sizes; (void)n_in; (void)out_size;
  const float* x  = (const float*)d_in[0];
  const float* Wg = (const float*)d_in[1];
  const float* bg = (const float*)d_in[2];
  const float* w1 = (const float*)d_in[3];
  const float* w3 = (const float*)d_in[4];
  const float* w2 = (const float*)d_in[5];
  float* out = (float*)d_out;

  char* ws = (char*)d_ws;
  int*   tok_ids = (int*)ws;               // 262144 B
  float* gates   = (float*)(ws + 262144);  // 262144 B
  int*   counts  = (int*)(ws + 524288);
  int*   offsets = (int*)(ws + 524352);
  u16*   xb      = (u16*)(ws + (1 << 20)); // 16.78 MB

  const size_t WEXP  = (size_t)HDIM * DDIM * 2;          // 4 MiB per weight per expert
  const size_t WALL  = 3ull * NEXP * WEXP;               // 100.7 MB
  const size_t HFULL = (size_t)ROWS_TOTAL * HDIM * 2;    // 67.1 MB
  const size_t base  = (1 << 20) + 16777216ull;

  hipMemsetAsync(counts, 0, 128, stream);
  hipMemsetAsync(out, 0, (size_t)TOKS * DDIM * 4, stream);

  cvt_x_kernel<<<TOKS * DDIM / (256 * 8), 256, 0, stream>>>(x, xb);
  router_kernel<<<TOKS / 4, 256, 0, stream>>>(x, Wg, bg, counts, tok_ids, gates);
  offsets_kernel<<<1, 64, 0, stream>>>(counts, offsets);

  if (ws_size >= base + WALL + HFULL) {
    // Mode A: all weights converted once, single big ffn launches across experts
    u16* w1t = (u16*)(ws + base);
    u16* w3t = w1t + (size_t)NEXP * HDIM * DDIM;
    u16* w2t = w3t + (size_t)NEXP * HDIM * DDIM;
    u16* hb  = w2t + (size_t)NEXP * HDIM * DDIM;
    cvt_wT_kernel<<<dim3(HDIM / 64, DDIM / 64, NEXP), 256, 0, stream>>>(w1, w1t, DDIM, HDIM);
    cvt_wT_kernel<<<dim3(HDIM / 64, DDIM / 64, NEXP), 256, 0, stream>>>(w3, w3t, DDIM, HDIM);
    cvt_wT_kernel<<<dim3(DDIM / 64, HDIM / 64, NEXP), 256, 0, stream>>>(w2, w2t, HDIM, DDIM);
    ffn1_kernel<<<dim3(64, HDIM / 128, NEXP), 256, 0, stream>>>(
        xb, w1t, w3t, tok_ids, counts, offsets, hb, 0, HDIM, -1);
    ffn2_kernel<<<dim3(64, DDIM / 128, NEXP), 256, 0, stream>>>(
        hb, w2t, tok_ids, gates, counts, offsets, out, 0, HDIM, -1);
  } else {
    // Mode B: per-expert weight buffers + h chunking
    int hw = 128;
    const int cand[5] = {2048, 1024, 512, 256, 128};
    for (int i = 0; i < 5; ++i)
      if (base + 3 * WEXP + (size_t)TOKS * cand[i] * 2 <= ws_size) { hw = cand[i]; break; }
    u16* w1t = (u16*)(ws + base);
    u16* w3t = w1t + (size_t)HDIM * DDIM;
    u16* w2t = w3t + (size_t)HDIM * DDIM;
    u16* hb  = w2t + (size_t)HDIM * DDIM;
    for (int e = 0; e < NEXP; ++e) {
      cvt_wT_kernel<<<dim3(HDIM / 64, DDIM / 64, 1), 256, 0, stream>>>(
          w1 + (size_t)e * DDIM * HDIM, w1t, DDIM, HDIM);
      cvt_wT_kernel<<<dim3(HDIM / 64, DDIM / 64, 1), 256, 0, stream>>>(
          w3 + (size_t)e * DDIM * HDIM, w3t, DDIM, HDIM);
      cvt_wT_kernel<<<dim3(DDIM / 64, HDIM / 64, 1), 256, 0, stream>>>(
          w2 + (size_t)e * HDIM * DDIM, w2t, HDIM, DDIM);
      for (int nbase = 0; nbase < HDIM; nbase += hw) {
        ffn1_kernel<<<dim3(64, hw / 128, 1), 256, 0, stream>>>(
            xb, w1t, w3t, tok_ids, counts, offsets, hb, nbase, hw, e);
        ffn2_kernel<<<dim3(64, DDIM / 128, 1), 256, 0, stream>>>(
            hb, w2t, tok_ids, gates, counts, offsets, out, nbase, hw, e);
      }
    }
  }
}